// Round 3
// baseline (5469.387 us; speedup 1.0000x reference)
//
#include <hip/hip_runtime.h>

static constexpr int BATCH = 512;
static constexpr int TT    = 1020;   // conv output length (1024 - 5 + 1)
static constexpr int MM    = BATCH * TT;  // 522240 rows for xg GEMMs

typedef __bf16 bf8 __attribute__((ext_vector_type(8)));
typedef float  f4v __attribute__((ext_vector_type(4)));

// ---- fast device nonlinearities (1-ulp hw exp2/rcp; fine vs 1.76e-3 budget) ----
__device__ __forceinline__ float fsig(float x) {
  float e = __builtin_amdgcn_exp2f(x * -1.442695041f);
  return __builtin_amdgcn_rcpf(1.0f + e);
}
__device__ __forceinline__ float ftanh(float x) {
  float e = __builtin_amdgcn_exp2f(x * 2.885390082f); // e^(2x)
  return 1.0f - 2.0f * __builtin_amdgcn_rcpf(e + 1.0f);
}

__device__ __forceinline__ f4v mfma16(bf8 a, bf8 b, f4v c) {
  return __builtin_amdgcn_mfma_f32_16x16x32_bf16(a, b, c, 0, 0, 0);
}

// =====================================================================
// W prepack: conv_w[128co][128ci][5k] fp32 -> per-wave-contiguous bf16
// MFMA B-fragments, hi/lo split.
// Layout: frag_block = (k*8 + ct)*4 + ch  (ct: co-tile of 16, ch: ci-chunk
// of 32); within block: [plane(2)][lane(64)][8 bf16] = 2 x 1KiB.
// Lane mapping matches mfma_16x16x32 B: co = ct*16 + (lane&15),
// ci = ch*32 + 8*(lane>>4) + j.
// =====================================================================
__global__ __launch_bounds__(64) void pack_w_kernel(
    const float* __restrict__ w, ushort* __restrict__ wp) {
  const int lane = threadIdx.x;
  const int ch = blockIdx.x & 3;
  const int ct = (blockIdx.x >> 2) & 7;
  const int k  = blockIdx.x >> 5;          // 0..4
  const int co  = ct * 16 + (lane & 15);
  const int ci0 = ch * 32 + (lane >> 4) * 8;
  ushort hi[8], lo[8];
#pragma unroll
  for (int j = 0; j < 8; ++j) {
    const float v = w[(size_t)(co * 128 + ci0 + j) * 5 + k];
    const unsigned u = __float_as_uint(v);
    const float hf = __uint_as_float(u & 0xffff0000u);
    hi[j] = (ushort)(u >> 16);
    lo[j] = (ushort)(__float_as_uint(v - hf) >> 16);
  }
  ushort* d0 = wp + ((size_t)blockIdx.x * 2 + 0) * 512 + (size_t)lane * 8;
  ushort* d1 = d0 + 512;
#pragma unroll
  for (int j = 0; j < 8; ++j) { d0[j] = hi[j]; d1[j] = lo[j]; }
}

// =====================================================================
// conv1d valid K=5 as MFMA implicit GEMM (bf16 hi/lo 3-pass split).
// C[co][l] = sum_{ci,k} W[co][ci][k] * X[ci][l+k]
// A = X (M=l), B = W (N=co): the 5 tap-shifted X fragments are a +k row
// offset in LDS and get reused across 4 co-tiles.
// Block: 256 thr = 4 waves; tile 64co x 256l; wave = 64l x 64co
//   (4 m-tiles x 4 co-tiles of 16x16), acc = 64 VGPR.
// K loop: 4 ci-chunks of 32 (one mfma K-step per tap per chunk).
// LDS xT[plane][260 l][32 ci] bf16, row stride 40 ushorts (80B):
//   staging b32 writes 2-way banked (free, m136), frag ds_read_b128
//   spreads 8 dwords/bank (ideal).  41.6 KB -> 3 blocks/CU.
// =====================================================================
__global__ __launch_bounds__(256) void conv_mfma_kernel(
    const float* __restrict__ x, const ushort* __restrict__ wp,
    const float* __restrict__ bias, float* __restrict__ c) {
  __shared__ ushort xT[2][260][40];
  const int b    = blockIdx.z;
  const int cb   = blockIdx.x;            // co-block 0..1
  const int l0   = blockIdx.y * 256;      // l-block 0..3
  const int tid  = threadIdx.x;
  const int lane = tid & 63;
  const int wv   = tid >> 6;              // wave: l-range wv*64
  const int lrow = lane & 15;
  const int lgrp = lane >> 4;

  f4v acc[4][4];                          // [m-tile][co-tile]
#pragma unroll
  for (int m = 0; m < 4; ++m)
#pragma unroll
    for (int t = 0; t < 4; ++t) acc[m][t] = (f4v){0.f, 0.f, 0.f, 0.f};

  const int sp  = tid & 15;               // staging: ci-pair
  const int slq = tid >> 4;               // staging: l-quad group

  for (int ch = 0; ch < 4; ++ch) {
    const int ci0 = ch * 32;
    __syncthreads();
    // ---- stage x chunk: fp32 -> bf16 hi/lo, transposed [l][ci] ----
    {
      const float* xr0 = x + ((size_t)b * 128 + ci0 + 2 * sp) * 1024 + l0;
      const float* xr1 = xr0 + 1024;
      for (int j = 0; j < 5; ++j) {
        const int l = slq * 4 + 64 * j;
        if (l >= 260) break;              // only slq==0 runs j==4
        const bool ok = (l0 + l) < 1024;  // whole-float4 validity (no straddle)
        float4 a0 = make_float4(0.f, 0.f, 0.f, 0.f);
        float4 a1 = make_float4(0.f, 0.f, 0.f, 0.f);
        if (ok) { a0 = *(const float4*)(xr0 + l); a1 = *(const float4*)(xr1 + l); }
        const float v0[4] = {a0.x, a0.y, a0.z, a0.w};
        const float v1[4] = {a1.x, a1.y, a1.z, a1.w};
#pragma unroll
        for (int e = 0; e < 4; ++e) {
          const unsigned u0 = __float_as_uint(v0[e]);
          const unsigned u1 = __float_as_uint(v1[e]);
          const unsigned h0 = u0 & 0xffff0000u;
          const unsigned h1 = u1 & 0xffff0000u;
          const float l0f = v0[e] - __uint_as_float(h0);
          const float l1f = v1[e] - __uint_as_float(h1);
          const unsigned hp = (u0 >> 16) | h1;
          const unsigned lp = (__float_as_uint(l0f) >> 16) |
                              (__float_as_uint(l1f) & 0xffff0000u);
          *(unsigned*)&xT[0][l + e][2 * sp] = hp;
          *(unsigned*)&xT[1][l + e][2 * sp] = lp;
        }
      }
    }
    __syncthreads();
    // ---- compute: per tap, X frags reused across 4 co-tiles ----
#pragma unroll
    for (int k = 0; k < 5; ++k) {
      bf8 xa[4][2];
#pragma unroll
      for (int m = 0; m < 4; ++m) {
        const int row = wv * 64 + m * 16 + lrow + k;
        xa[m][0] = *(const bf8*)&xT[0][row][lgrp * 8];
        xa[m][1] = *(const bf8*)&xT[1][row][lgrp * 8];
      }
#pragma unroll
      for (int ct = 0; ct < 4; ++ct) {
        const ushort* wf =
            wp + (size_t)(((k * 8 + cb * 4 + ct) * 4 + ch) * 2) * 512 + lane * 8;
        const bf8 wh = *(const bf8*)wf;
        const bf8 wl = *(const bf8*)(wf + 512);
#pragma unroll
        for (int m = 0; m < 4; ++m) {
          acc[m][ct] = mfma16(xa[m][0], wh, acc[m][ct]); // hi*hi
          acc[m][ct] = mfma16(xa[m][1], wh, acc[m][ct]); // lo*hi
          acc[m][ct] = mfma16(xa[m][0], wl, acc[m][ct]); // hi*lo
        }
      }
    }
  }
  // ---- epilogue: bias + store; C/D: col(lane&15)=co, row=(lane>>4)*4+reg=l
#pragma unroll
  for (int ct = 0; ct < 4; ++ct) {
    const int co = cb * 64 + ct * 16 + lrow;
    const float bv = bias[co];
    float* crow = c + (size_t)b * 130560 + (size_t)co * TT;
#pragma unroll
    for (int m = 0; m < 4; ++m) {
      const int l = l0 + wv * 64 + m * 16 + lgrp * 4;
      if (l < TT) {
        float4 st;
        st.x = acc[m][ct][0] + bv; st.y = acc[m][ct][1] + bv;
        st.z = acc[m][ct][2] + bv; st.w = acc[m][ct][3] + bv;
        *(float4*)(crow + l) = st;
      }
    }
  }
}

// =====================================================================
// xg GEMM: A[MM][K] @ W[N][K]^T + (bih+bhh), output TRANSPOSED per batch:
// xgT[b][n][t]  (so the LSTM streams each gate contiguously over t).
// block: 64m x 64n, thread 4x4, K staged in chunks of <=64 through LDS.
// =====================================================================
template <int K>
__global__ __launch_bounds__(256) void gemm_xg(
    const float* __restrict__ A, const float* __restrict__ W,
    const float* __restrict__ bih, const float* __restrict__ bhh,
    float* __restrict__ xgT, const int Ntot) {
  constexpr int KC = (K > 64) ? 64 : K;
  constexpr int LITEMS = (16 * KC) / 256 > 0 ? (16 * KC) / 256 : 1; // float4s per thread
  __shared__ float At[KC][68];
  __shared__ float Wt[KC][68];
  const int m0 = blockIdx.x * 64;
  const int n0 = blockIdx.y * 64;
  const int tid = threadIdx.x;
  const int tn = tid & 15;   // n = n0 + tn*4 + j
  const int tm = tid >> 4;   // m = m0 + tm*4 + i

  float acc[4][4];
#pragma unroll
  for (int i = 0; i < 4; ++i)
#pragma unroll
    for (int j = 0; j < 4; ++j) acc[i][j] = 0.f;

  for (int kc = 0; kc < K; kc += KC) {
    __syncthreads();
#pragma unroll
    for (int it = 0; it < LITEMS; ++it) {
      const int i  = tid + it * 256;
      const int r  = i / (KC / 4);
      const int c4 = i % (KC / 4);
      const float4 v = *(const float4*)(A + (size_t)(m0 + r) * K + kc + c4 * 4);
      At[c4 * 4 + 0][r] = v.x; At[c4 * 4 + 1][r] = v.y;
      At[c4 * 4 + 2][r] = v.z; At[c4 * 4 + 3][r] = v.w;
    }
#pragma unroll
    for (int it = 0; it < LITEMS; ++it) {
      const int i  = tid + it * 256;
      const int r  = i / (KC / 4);
      const int c4 = i % (KC / 4);
      const float4 v = *(const float4*)(W + (size_t)(n0 + r) * K + kc + c4 * 4);
      Wt[c4 * 4 + 0][r] = v.x; Wt[c4 * 4 + 1][r] = v.y;
      Wt[c4 * 4 + 2][r] = v.z; Wt[c4 * 4 + 3][r] = v.w;
    }
    __syncthreads();
#pragma unroll 8
    for (int k = 0; k < KC; ++k) {
      const float4 av = *(const float4*)&At[k][tm * 4];
      const float4 wv = *(const float4*)&Wt[k][tn * 4];
      const float a[4] = {av.x, av.y, av.z, av.w};
      const float wr[4] = {wv.x, wv.y, wv.z, wv.w};
#pragma unroll
      for (int i = 0; i < 4; ++i)
#pragma unroll
        for (int j = 0; j < 4; ++j)
          acc[i][j] = fmaf(a[i], wr[j], acc[i][j]);
    }
  }
  // epilogue: bias + transposed scatter (exact magic div by 1020)
  float bv[4];
#pragma unroll
  for (int j = 0; j < 4; ++j)
    bv[j] = bih[n0 + tn * 4 + j] + bhh[n0 + tn * 4 + j];
#pragma unroll
  for (int i = 0; i < 4; ++i) {
    const int m  = m0 + tm * 4 + i;
    const int bb = (int)(((unsigned long long)m * 4311810306ULL) >> 42); // m/1020 exact
    const int t  = m - bb * TT;
    float* dst = xgT + ((size_t)bb * Ntot + n0 + tn * 4) * TT + t;
#pragma unroll
    for (int j = 0; j < 4; ++j) dst[(size_t)j * TT] = acc[i][j] + bv[j];
  }
}

// =====================================================================
// LSTM recurrence, multi-chain: NC batch elements per wave (Whh shared).
// R2 finding: 1 chain/wave = 1075 cyc/step vs ~270 cyc issue -> 75%
// latency stall (0.5 waves/SIMD, nothing to fill readlane->fma->bpermute->
// exp2 chain). NC chains interleave in one wave: chain A's stalls are
// filled by B/C/D's instructions; weights shared so 0 extra VGPR for W.
// Streaming: 3-slot x 4-step register ring (1020 = 85*12), prefetch 8
// steps ahead, slots statically indexed (unrolled); the 4-substep loop is
// kept ROLLED (unroll 1, select-based component extraction) so the body
// stays ~14 KB (I-cache) without scratch (rule #20).
// =====================================================================
template <int H, int NC, bool FINAL>
__global__ __launch_bounds__(64, 1) void lstm_kernel(
    const float* __restrict__ xgT, const float* __restrict__ Whh,
    float* __restrict__ hout) {
  constexpr int G   = 4 * H;
  constexpr int GPL = G / 64;  // gate streams per chain: 2 (H=32), 1 (H=16)
  constexpr int KG  = H / 4;   // k-group size
  const int b0   = blockIdx.x * NC;
  const int lane = threadIdx.x;

  float w0[H];
  float w1[GPL == 2 ? H : 1];
#pragma unroll
  for (int k = 0; k < H; ++k) {
    w0[k] = Whh[lane * H + k];
    if constexpr (GPL == 2) w1[k] = Whh[(lane + 64) * H + k];
  }

  const float* p0[NC];
  const float* p1[GPL == 2 ? NC : 1];
  float hs[NC], cs[NC];
  float4 buf0[NC][3];
  float4 buf1[GPL == 2 ? NC : 1][3];
#pragma unroll
  for (int cc = 0; cc < NC; ++cc) {
    p0[cc] = xgT + ((size_t)(b0 + cc) * G + lane) * TT;
    hs[cc] = 0.f; cs[cc] = 0.f;
#pragma unroll
    for (int sl = 0; sl < 3; ++sl)
      buf0[cc][sl] = *(const float4*)(p0[cc] + 4 * sl);
    if constexpr (GPL == 2) {
      p1[cc] = xgT + ((size_t)(b0 + cc) * G + lane + 64) * TT;
#pragma unroll
      for (int sl = 0; sl < 3; ++sl)
        buf1[cc][sl] = *(const float4*)(p1[cc] + 4 * sl);
    }
  }

  for (int t12 = 0; t12 < TT; t12 += 12) {
#pragma unroll
    for (int sl = 0; sl < 3; ++sl) {
#pragma unroll 1
      for (int s = 0; s < 4; ++s) {
        const int t = t12 + sl * 4 + s;
#pragma unroll
        for (int cc = 0; cc < NC; ++cc) {
          const float4 v0 = buf0[cc][sl];
          const float xg0 =
              (s == 0) ? v0.x : (s == 1) ? v0.y : (s == 2) ? v0.z : v0.w;
          float xg1 = 0.f;
          if constexpr (GPL == 2) {
            const float4 v1 = buf1[cc][sl];
            xg1 = (s == 0) ? v1.x : (s == 1) ? v1.y : (s == 2) ? v1.z : v1.w;
          }
          // recurrent matvec, 4-way split accumulators (short dep chains)
          float q0[4], q1[4];
          q0[0] = xg0; q0[1] = 0.f; q0[2] = 0.f; q0[3] = 0.f;
          if constexpr (GPL == 2) {
            q1[0] = xg1; q1[1] = 0.f; q1[2] = 0.f; q1[3] = 0.f;
          }
#pragma unroll
          for (int g = 0; g < 4; ++g)
#pragma unroll
            for (int k8 = 0; k8 < KG; ++k8) {
              const int k = g * KG + k8;
              const float hk = __uint_as_float(
                  __builtin_amdgcn_readlane(__float_as_uint(hs[cc]), k));
              q0[g] = fmaf(w0[k], hk, q0[g]);
              if constexpr (GPL == 2) q1[g] = fmaf(w1[k], hk, q1[g]);
            }
          const float acc0 = (q0[0] + q0[1]) + (q0[2] + q0[3]);
          float acc1 = 0.f;
          if constexpr (GPL == 2) acc1 = (q1[0] + q1[1]) + (q1[2] + q1[3]);

          // gather i,f,g,o raw gate values to every lane
          float iraw, fraw, graw, oraw;
          if constexpr (H == 32) {
            const float r0 = __shfl_xor(acc0, 32, 64);
            const float r1 = __shfl_xor(acc1, 32, 64);
            const bool hi = lane >= 32;
            iraw = hi ? r0 : acc0;
            fraw = hi ? acc0 : r0;
            graw = hi ? r1 : acc1;
            oraw = hi ? acc1 : r1;
          } else {
            const float x1 = __shfl_xor(acc0, 16, 64);
            const float x2 = __shfl_xor(acc0, 32, 64);
            const float x3 = __shfl_xor(acc0, 48, 64);
            const int q = lane >> 4;
            const float t0 = (q & 1) ? x1 : acc0;
            const float t1 = (q & 1) ? acc0 : x1;
            const float u0 = (q & 1) ? x3 : x2;
            const float u1 = (q & 1) ? x2 : x3;
            const bool hi2 = q >= 2;
            iraw = hi2 ? u0 : t0;
            fraw = hi2 ? u1 : t1;
            graw = hi2 ? t0 : u0;
            oraw = hi2 ? t1 : u1;
          }
          const float ig = fsig(iraw);
          const float fg = fsig(fraw);
          const float gg = ftanh(graw);
          const float og = fsig(oraw);
          cs[cc] = fmaf(fg, cs[cc], ig * gg);
          hs[cc] = og * ftanh(cs[cc]);
          if constexpr (!FINAL) {
            if (lane < H)
              hout[((size_t)(b0 + cc) * TT + t) * H + lane] = hs[cc];
          } else {
            if (t == TT - 1 && lane < H)
              hout[(b0 + cc) * H + lane] = hs[cc];
          }
        }
      }
      // prefetch slot sl for t12 + 12 + 4*sl (lead: 8 steps)
      {
        const int tp = t12 + 12 + 4 * sl;
        if (tp < TT) {
#pragma unroll
          for (int cc = 0; cc < NC; ++cc) {
            buf0[cc][sl] = *(const float4*)(p0[cc] + tp);
            if constexpr (GPL == 2)
              buf1[cc][sl] = *(const float4*)(p1[cc] + tp);
          }
        }
      }
    }
  }
}

// =====================================================================
extern "C" void kernel_launch(void* const* d_in, const int* in_sizes, int n_in,
                              void* d_out, int out_size, void* d_ws, size_t ws_size,
                              hipStream_t stream) {
  const float* x      = (const float*)d_in[0];
  const float* conv_w = (const float*)d_in[1];
  const float* conv_b = (const float*)d_in[2];
  const float* Wih1   = (const float*)d_in[3];
  const float* Whh1   = (const float*)d_in[4];
  const float* bih1   = (const float*)d_in[5];
  const float* bhh1   = (const float*)d_in[6];
  const float* Wih2   = (const float*)d_in[7];
  const float* Whh2   = (const float*)d_in[8];
  const float* bih2   = (const float*)d_in[9];
  const float* bhh2   = (const float*)d_in[10];
  const float* Wih3   = (const float*)d_in[11];
  const float* Whh3   = (const float*)d_in[12];
  const float* bih3   = (const float*)d_in[13];
  const float* bhh3   = (const float*)d_in[14];
  float* out = (float*)d_out;
  float* ws  = (float*)d_ws;

  // workspace layout (floats); regions reused once dead:
  float* c    = ws;                    // 66,846,720  : conv out == seq (flat view)
  float* xgT1 = ws + 66846720;         // 66,846,720  : layer-1 gates, transposed
  float* h1   = ws + 133693440;        // 16,711,680  : layer-1 hidden
  float* xgT2 = c;                     // 33,423,360  : reuse conv region
  float* h2   = h1;                    //  8,355,840  : reuse h1 region
  float* xgT3 = xgT1;                  // 66,846,720  : reuse xgT1 region
  // wpack lives at the head of the h1 region (163,840 floats) — it is only
  // read by conv_mfma, which completes before lstm1 writes h1.
  ushort* wpack = (ushort*)h1;
  // total footprint: 601.6 MB (unchanged)

  pack_w_kernel<<<160, 64, 0, stream>>>(conv_w, wpack);
  conv_mfma_kernel<<<dim3(2, 4, BATCH), 256, 0, stream>>>(x, wpack, conv_b, c);
  // seq is c reinterpreted as [B*1020][128] (the reference's .view quirk)
  gemm_xg<128><<<dim3(MM / 64, 2), 256, 0, stream>>>(c, Wih1, bih1, bhh1, xgT1, 128);
  lstm_kernel<32, 4, false><<<BATCH / 4, 64, 0, stream>>>(xgT1, Whh1, h1);
  gemm_xg<32><<<dim3(MM / 64, 1), 256, 0, stream>>>(h1, Wih2, bih2, bhh2, xgT2, 64);
  lstm_kernel<16, 8, false><<<BATCH / 8, 64, 0, stream>>>(xgT2, Whh2, h2);
  gemm_xg<16><<<dim3(MM / 64, 2), 256, 0, stream>>>(h2, Wih3, bih3, bhh3, xgT3, 128);
  lstm_kernel<32, 4, true><<<BATCH / 4, 64, 0, stream>>>(xgT3, Whh3, out);
}

// Round 6
// 2063.515 us; speedup vs baseline: 2.6505x; 2.6505x over previous
//
#include <hip/hip_runtime.h>

static constexpr int BATCH = 512;
static constexpr int TT    = 1020;   // conv output length (1024 - 5 + 1)
static constexpr int MM    = BATCH * TT;  // 522240 rows for xg GEMMs

typedef __bf16 bf8 __attribute__((ext_vector_type(8)));
typedef float  f4v __attribute__((ext_vector_type(4)));
typedef float  f2v __attribute__((ext_vector_type(2)));

// ---- fast device nonlinearities (1-ulp hw exp2/rcp; fine vs 1.76e-3 budget) ----
__device__ __forceinline__ float fsig(float x) {
  float e = __builtin_amdgcn_exp2f(x * -1.442695041f);
  return __builtin_amdgcn_rcpf(1.0f + e);
}
__device__ __forceinline__ float ftanh(float x) {
  float e = __builtin_amdgcn_exp2f(x * 2.885390082f); // e^(2x)
  return 1.0f - 2.0f * __builtin_amdgcn_rcpf(e + 1.0f);
}

__device__ __forceinline__ f4v mfma16(bf8 a, bf8 b, f4v c) {
  return __builtin_amdgcn_mfma_f32_16x16x32_bf16(a, b, c, 0, 0, 0);
}

// =====================================================================
// W prepack: conv_w[128co][128ci][5k] fp32 -> per-wave-contiguous bf16
// MFMA B-fragments, hi/lo split.  (verified R2)
// =====================================================================
__global__ __launch_bounds__(64) void pack_w_kernel(
    const float* __restrict__ w, ushort* __restrict__ wp) {
  const int lane = threadIdx.x;
  const int ch = blockIdx.x & 3;
  const int ct = (blockIdx.x >> 2) & 7;
  const int k  = blockIdx.x >> 5;          // 0..4
  const int co  = ct * 16 + (lane & 15);
  const int ci0 = ch * 32 + (lane >> 4) * 8;
  ushort hi[8], lo[8];
#pragma unroll
  for (int j = 0; j < 8; ++j) {
    const float v = w[(size_t)(co * 128 + ci0 + j) * 5 + k];
    const unsigned u = __float_as_uint(v);
    const float hf = __uint_as_float(u & 0xffff0000u);
    hi[j] = (ushort)(u >> 16);
    lo[j] = (ushort)(__float_as_uint(v - hf) >> 16);
  }
  ushort* d0 = wp + ((size_t)blockIdx.x * 2 + 0) * 512 + (size_t)lane * 8;
  ushort* d1 = d0 + 512;
#pragma unroll
  for (int j = 0; j < 8; ++j) { d0[j] = hi[j]; d1[j] = lo[j]; }
}

// =====================================================================
// conv1d valid K=5 as MFMA implicit GEMM (bf16 hi/lo 3-pass). (verified R2)
// =====================================================================
__global__ __launch_bounds__(256) void conv_mfma_kernel(
    const float* __restrict__ x, const ushort* __restrict__ wp,
    const float* __restrict__ bias, float* __restrict__ c) {
  __shared__ ushort xT[2][260][40];
  const int b    = blockIdx.z;
  const int cb   = blockIdx.x;            // co-block 0..1
  const int l0   = blockIdx.y * 256;      // l-block 0..3
  const int tid  = threadIdx.x;
  const int lane = tid & 63;
  const int wv   = tid >> 6;              // wave: l-range wv*64
  const int lrow = lane & 15;
  const int lgrp = lane >> 4;

  f4v acc[4][4];                          // [m-tile][co-tile]
#pragma unroll
  for (int m = 0; m < 4; ++m)
#pragma unroll
    for (int t = 0; t < 4; ++t) acc[m][t] = (f4v){0.f, 0.f, 0.f, 0.f};

  const int sp  = tid & 15;               // staging: ci-pair
  const int slq = tid >> 4;               // staging: l-quad group

  for (int ch = 0; ch < 4; ++ch) {
    const int ci0 = ch * 32;
    __syncthreads();
    // ---- stage x chunk: fp32 -> bf16 hi/lo, transposed [l][ci] ----
    {
      const float* xr0 = x + ((size_t)b * 128 + ci0 + 2 * sp) * 1024 + l0;
      const float* xr1 = xr0 + 1024;
      for (int j = 0; j < 5; ++j) {
        const int l = slq * 4 + 64 * j;
        if (l >= 260) break;              // only slq==0 runs j==4
        const bool ok = (l0 + l) < 1024;  // whole-float4 validity (no straddle)
        float4 a0 = make_float4(0.f, 0.f, 0.f, 0.f);
        float4 a1 = make_float4(0.f, 0.f, 0.f, 0.f);
        if (ok) { a0 = *(const float4*)(xr0 + l); a1 = *(const float4*)(xr1 + l); }
        const float v0[4] = {a0.x, a0.y, a0.z, a0.w};
        const float v1[4] = {a1.x, a1.y, a1.z, a1.w};
#pragma unroll
        for (int e = 0; e < 4; ++e) {
          const unsigned u0 = __float_as_uint(v0[e]);
          const unsigned u1 = __float_as_uint(v1[e]);
          const unsigned h0 = u0 & 0xffff0000u;
          const unsigned h1 = u1 & 0xffff0000u;
          const float l0f = v0[e] - __uint_as_float(h0);
          const float l1f = v1[e] - __uint_as_float(h1);
          const unsigned hp = (u0 >> 16) | h1;
          const unsigned lp = (__float_as_uint(l0f) >> 16) |
                              (__float_as_uint(l1f) & 0xffff0000u);
          *(unsigned*)&xT[0][l + e][2 * sp] = hp;
          *(unsigned*)&xT[1][l + e][2 * sp] = lp;
        }
      }
    }
    __syncthreads();
    // ---- compute: per tap, X frags reused across 4 co-tiles ----
#pragma unroll
    for (int k = 0; k < 5; ++k) {
      bf8 xa[4][2];
#pragma unroll
      for (int m = 0; m < 4; ++m) {
        const int row = wv * 64 + m * 16 + lrow + k;
        xa[m][0] = *(const bf8*)&xT[0][row][lgrp * 8];
        xa[m][1] = *(const bf8*)&xT[1][row][lgrp * 8];
      }
#pragma unroll
      for (int ct = 0; ct < 4; ++ct) {
        const ushort* wf =
            wp + (size_t)(((k * 8 + cb * 4 + ct) * 4 + ch) * 2) * 512 + lane * 8;
        const bf8 wh = *(const bf8*)wf;
        const bf8 wl = *(const bf8*)(wf + 512);
#pragma unroll
        for (int m = 0; m < 4; ++m) {
          acc[m][ct] = mfma16(xa[m][0], wh, acc[m][ct]); // hi*hi
          acc[m][ct] = mfma16(xa[m][1], wh, acc[m][ct]); // lo*hi
          acc[m][ct] = mfma16(xa[m][0], wl, acc[m][ct]); // hi*lo
        }
      }
    }
  }
  // ---- epilogue: bias + store; C/D: col(lane&15)=co, row=(lane>>4)*4+reg=l
#pragma unroll
  for (int ct = 0; ct < 4; ++ct) {
    const int co = cb * 64 + ct * 16 + lrow;
    const float bv = bias[co];
    float* crow = c + (size_t)b * 130560 + (size_t)co * TT;
#pragma unroll
    for (int m = 0; m < 4; ++m) {
      const int l = l0 + wv * 64 + m * 16 + lgrp * 4;
      if (l < TT) {
        float4 st;
        st.x = acc[m][ct][0] + bv; st.y = acc[m][ct][1] + bv;
        st.z = acc[m][ct][2] + bv; st.w = acc[m][ct][3] + bv;
        *(float4*)(crow + l) = st;
      }
    }
  }
}

// =====================================================================
// xg GEMM: A[MM][K] @ W[N][K]^T + (bih+bhh), transposed output. (verified R2)
// =====================================================================
template <int K>
__global__ __launch_bounds__(256) void gemm_xg(
    const float* __restrict__ A, const float* __restrict__ W,
    const float* __restrict__ bih, const float* __restrict__ bhh,
    float* __restrict__ xgT, const int Ntot) {
  constexpr int KC = (K > 64) ? 64 : K;
  constexpr int LITEMS = (16 * KC) / 256 > 0 ? (16 * KC) / 256 : 1; // float4s per thread
  __shared__ float At[KC][68];
  __shared__ float Wt[KC][68];
  const int m0 = blockIdx.x * 64;
  const int n0 = blockIdx.y * 64;
  const int tid = threadIdx.x;
  const int tn = tid & 15;   // n = n0 + tn*4 + j
  const int tm = tid >> 4;   // m = m0 + tm*4 + i

  float acc[4][4];
#pragma unroll
  for (int i = 0; i < 4; ++i)
#pragma unroll
    for (int j = 0; j < 4; ++j) acc[i][j] = 0.f;

  for (int kc = 0; kc < K; kc += KC) {
    __syncthreads();
#pragma unroll
    for (int it = 0; it < LITEMS; ++it) {
      const int i  = tid + it * 256;
      const int r  = i / (KC / 4);
      const int c4 = i % (KC / 4);
      const float4 v = *(const float4*)(A + (size_t)(m0 + r) * K + kc + c4 * 4);
      At[c4 * 4 + 0][r] = v.x; At[c4 * 4 + 1][r] = v.y;
      At[c4 * 4 + 2][r] = v.z; At[c4 * 4 + 3][r] = v.w;
    }
#pragma unroll
    for (int it = 0; it < LITEMS; ++it) {
      const int i  = tid + it * 256;
      const int r  = i / (KC / 4);
      const int c4 = i % (KC / 4);
      const float4 v = *(const float4*)(W + (size_t)(n0 + r) * K + kc + c4 * 4);
      Wt[c4 * 4 + 0][r] = v.x; Wt[c4 * 4 + 1][r] = v.y;
      Wt[c4 * 4 + 2][r] = v.z; Wt[c4 * 4 + 3][r] = v.w;
    }
    __syncthreads();
#pragma unroll 8
    for (int k = 0; k < KC; ++k) {
      const float4 av = *(const float4*)&At[k][tm * 4];
      const float4 wv = *(const float4*)&Wt[k][tn * 4];
      const float a[4] = {av.x, av.y, av.z, av.w};
      const float wr[4] = {wv.x, wv.y, wv.z, wv.w};
#pragma unroll
      for (int i = 0; i < 4; ++i)
#pragma unroll
        for (int j = 0; j < 4; ++j)
          acc[i][j] = fmaf(a[i], wr[j], acc[i][j]);
    }
  }
  // epilogue: bias + transposed scatter (exact magic div by 1020)
  float bv[4];
#pragma unroll
  for (int j = 0; j < 4; ++j)
    bv[j] = bih[n0 + tn * 4 + j] + bhh[n0 + tn * 4 + j];
#pragma unroll
  for (int i = 0; i < 4; ++i) {
    const int m  = m0 + tm * 4 + i;
    const int bb = (int)(((unsigned long long)m * 4311810306ULL) >> 42); // m/1020 exact
    const int t  = m - bb * TT;
    float* dst = xgT + ((size_t)bb * Ntot + n0 + tn * 4) * TT + t;
#pragma unroll
    for (int j = 0; j < 4; ++j) dst[(size_t)j * TT] = acc[i][j] + bv[j];
  }
}

// =====================================================================
// LSTM recurrence: one wave per batch element (R2-proven 457us streaming
// structure). This round's de-risked critical-path cut:
//  - h broadcast via 128B LDS (1 ds_write + H/4 broadcast ds_read_b128)
//    instead of 32 v_readlane (SGPR-hazard chain).     [plain HIP]
//  - matvec as float2 v_pk_fma_f32 (__builtin_elementwise_fma) -> half
//    the FMA issue slots.                               [generic builtin]
//  - gate exchange: R2-proven __shfl_xor (permlane swaps reverted —
//    suspected container-killer in R4/R5; retry later as isolated A/B).
// Single wave per block: DS ops are wave-ordered, no barrier needed.
// =====================================================================
template <int H, bool FINAL>
__global__ __launch_bounds__(64, 1) void lstm_kernel(
    const float* __restrict__ xgT, const float* __restrict__ Whh,
    float* __restrict__ hout) {
  constexpr int G   = 4 * H;
  constexpr int GPL = G / 64;  // 2 for H=32, 1 for H=16
  __shared__ __align__(16) float hlds[H];
  const int b    = blockIdx.x;
  const int lane = threadIdx.x;

  // weights as float2 pairs (per-lane rows of Whh)
  f2v w0[H / 2];
  f2v w1[GPL == 2 ? H / 2 : 1];
#pragma unroll
  for (int k = 0; k < H / 2; ++k) {
    w0[k] = (f2v){Whh[lane * H + 2 * k], Whh[lane * H + 2 * k + 1]};
    if constexpr (GPL == 2)
      w1[k] = (f2v){Whh[(lane + 64) * H + 2 * k], Whh[(lane + 64) * H + 2 * k + 1]};
  }

  const float* p0 = xgT + ((size_t)b * G + lane) * TT;
  const float* p1 = xgT + ((size_t)b * G + (GPL == 2 ? lane + 64 : lane)) * TT;

  float h = 0.f, c = 0.f;
  float4 cur0[4], cur1[4], nxt0[4], nxt1[4];
#pragma unroll
  for (int r = 0; r < 4; ++r) {
    cur0[r] = *(const float4*)(p0 + 4 * r);
    nxt0[r] = *(const float4*)(p0 + 16 + 4 * r);
    if constexpr (GPL == 2) {
      cur1[r] = *(const float4*)(p1 + 4 * r);
      nxt1[r] = *(const float4*)(p1 + 16 + 4 * r);
    }
  }

  for (int t16 = 0; t16 < TT; t16 += 16) {
#pragma unroll
    for (int r = 0; r < 4; ++r) {
      const int t4 = t16 + 4 * r;
      if (t4 >= TT) break;   // tail: TT=1020 = 63*16 + 12
#pragma unroll
      for (int s = 0; s < 4; ++s) {
        const float xg0 = ((const float*)&cur0[r])[s];
        float xg1 = 0.f;
        if constexpr (GPL == 2) xg1 = ((const float*)&cur1[r])[s];

        // ---- broadcast h via LDS (same-addr b128 reads: conflict-free;
        //      duplicate lanes write identical values -> benign) ----
        hlds[lane & (H - 1)] = h;
        f2v h2[H / 2];
#pragma unroll
        for (int j = 0; j < H / 4; ++j) {
          const float4 hv = *(const float4*)&hlds[4 * j];
          h2[2 * j]     = (f2v){hv.x, hv.y};
          h2[2 * j + 1] = (f2v){hv.z, hv.w};
        }

        // ---- recurrent matvec: packed fp32 fma, 2 split accumulators ----
        f2v qa0 = (f2v){xg0, 0.f}, qb0 = (f2v){0.f, 0.f};
        f2v qa1 = (f2v){xg1, 0.f}, qb1 = (f2v){0.f, 0.f};
#pragma unroll
        for (int j = 0; j < H / 2; j += 2) {
          qa0 = __builtin_elementwise_fma(w0[j],     h2[j],     qa0);
          qb0 = __builtin_elementwise_fma(w0[j + 1], h2[j + 1], qb0);
          if constexpr (GPL == 2) {
            qa1 = __builtin_elementwise_fma(w1[j],     h2[j],     qa1);
            qb1 = __builtin_elementwise_fma(w1[j + 1], h2[j + 1], qb1);
          }
        }
        const f2v qs0 = qa0 + qb0;
        const float acc0 = qs0.x + qs0.y;
        float acc1 = 0.f;
        if constexpr (GPL == 2) {
          const f2v qs1 = qa1 + qb1;
          acc1 = qs1.x + qs1.y;
        }

        // ---- gather i,f,g,o raw gate values (R2-proven shfl_xor) ----
        float iraw, fraw, graw, oraw;
        if constexpr (H == 32) {
          const float r0 = __shfl_xor(acc0, 32, 64);
          const float r1 = __shfl_xor(acc1, 32, 64);
          const bool hi = lane >= 32;
          iraw = hi ? r0 : acc0;
          fraw = hi ? acc0 : r0;
          graw = hi ? r1 : acc1;
          oraw = hi ? acc1 : r1;
        } else {
          const float x1 = __shfl_xor(acc0, 16, 64);
          const float x2 = __shfl_xor(acc0, 32, 64);
          const float x3 = __shfl_xor(acc0, 48, 64);
          const int q = lane >> 4;
          const float t0 = (q & 1) ? x1 : acc0;
          const float t1 = (q & 1) ? acc0 : x1;
          const float u0 = (q & 1) ? x3 : x2;
          const float u1 = (q & 1) ? x2 : x3;
          const bool hi2 = q >= 2;
          iraw = hi2 ? u0 : t0;
          fraw = hi2 ? u1 : t1;
          graw = hi2 ? t0 : u0;
          oraw = hi2 ? t1 : u1;
        }
        const float ig = fsig(iraw);
        const float fg = fsig(fraw);
        const float gg = ftanh(graw);
        const float og = fsig(oraw);
        c = fmaf(fg, c, ig * gg);
        h = og * ftanh(c);
        if constexpr (!FINAL) {
          if (lane < H) hout[((size_t)b * TT + (t4 + s)) * H + lane] = h;
        } else {
          if (t4 + s == TT - 1 && lane < H) hout[b * H + lane] = h;
        }
      }
    }
    // rotate double-buffer and prefetch t16+32 .. t16+47
#pragma unroll
    for (int r = 0; r < 4; ++r) {
      cur0[r] = nxt0[r];
      if constexpr (GPL == 2) cur1[r] = nxt1[r];
      const int tp = t16 + 32 + 4 * r;
      if (tp < TT) {
        nxt0[r] = *(const float4*)(p0 + tp);
        if constexpr (GPL == 2) nxt1[r] = *(const float4*)(p1 + tp);
      }
    }
  }
}

// =====================================================================
extern "C" void kernel_launch(void* const* d_in, const int* in_sizes, int n_in,
                              void* d_out, int out_size, void* d_ws, size_t ws_size,
                              hipStream_t stream) {
  const float* x      = (const float*)d_in[0];
  const float* conv_w = (const float*)d_in[1];
  const float* conv_b = (const float*)d_in[2];
  const float* Wih1   = (const float*)d_in[3];
  const float* Whh1   = (const float*)d_in[4];
  const float* bih1   = (const float*)d_in[5];
  const float* bhh1   = (const float*)d_in[6];
  const float* Wih2   = (const float*)d_in[7];
  const float* Whh2   = (const float*)d_in[8];
  const float* bih2   = (const float*)d_in[9];
  const float* bhh2   = (const float*)d_in[10];
  const float* Wih3   = (const float*)d_in[11];
  const float* Whh3   = (const float*)d_in[12];
  const float* bih3   = (const float*)d_in[13];
  const float* bhh3   = (const float*)d_in[14];
  float* out = (float*)d_out;
  float* ws  = (float*)d_ws;

  // workspace layout (floats); regions reused once dead:
  float* c    = ws;                    // 66,846,720  : conv out == seq (flat view)
  float* xgT1 = ws + 66846720;         // 66,846,720  : layer-1 gates, transposed
  float* h1   = ws + 133693440;        // 16,711,680  : layer-1 hidden
  float* xgT2 = c;                     // 33,423,360  : reuse conv region
  float* h2   = h1;                    //  8,355,840  : reuse h1 region
  float* xgT3 = xgT1;                  // 66,846,720  : reuse xgT1 region
  // wpack lives at the head of the h1 region (163,840 floats) — it is only
  // read by conv_mfma, which completes before lstm1 writes h1.
  ushort* wpack = (ushort*)h1;
  // total footprint: 601.6 MB (unchanged)

  pack_w_kernel<<<160, 64, 0, stream>>>(conv_w, wpack);
  conv_mfma_kernel<<<dim3(2, 4, BATCH), 256, 0, stream>>>(x, wpack, conv_b, c);
  // seq is c reinterpreted as [B*1020][128] (the reference's .view quirk)
  gemm_xg<128><<<dim3(MM / 64, 2), 256, 0, stream>>>(c, Wih1, bih1, bhh1, xgT1, 128);
  lstm_kernel<32, false><<<BATCH, 64, 0, stream>>>(xgT1, Whh1, h1);
  gemm_xg<32><<<dim3(MM / 64, 1), 256, 0, stream>>>(h1, Wih2, bih2, bhh2, xgT2, 64);
  lstm_kernel<16, false><<<BATCH, 64, 0, stream>>>(xgT2, Whh2, h2);
  gemm_xg<16><<<dim3(MM / 64, 2), 256, 0, stream>>>(h2, Wih3, bih3, bhh3, xgT3, 128);
  lstm_kernel<32, true><<<BATCH, 64, 0, stream>>>(xgT3, Whh3, out);
}